// Round 2
// baseline (870.138 us; speedup 1.0000x reference)
//
#include <hip/hip_runtime.h>
#include <hip/hip_bf16.h>

typedef __bf16 bf16x8 __attribute__((ext_vector_type(8)));
typedef float f32x4 __attribute__((ext_vector_type(4)));
typedef unsigned short ushort_t;

#define NN 8192
#define DD 128
#define KTOT 24576
#define SPLITS 16
#define KSPLIT 1536            // KTOT / SPLITS
#define NSTEP 48               // KSPLIT / 32
#define BM 128

typedef __attribute__((address_space(3))) unsigned int as3_u32;
typedef const __attribute__((address_space(1))) unsigned int as1_u32;

// ---------------------------------------------------------------------------
// Kernel 1: B[r][n] = sum_c x[r&8191][c] * sd[r>>13][c] * W[c][n]  (r in [0,24576))
// Output bf16 in MFMA-16x16x32 B-fragment order (one coalesced 16B load/lane).
// Also zeroes d_out (replaces the hipMemsetAsync dispatch).
// ---------------------------------------------------------------------------
__global__ __launch_bounds__(256) void bprep_kernel(
    const float* __restrict__ x, const float* __restrict__ W,
    const float* __restrict__ sd0, const float* __restrict__ sd1,
    const float* __restrict__ sd2, ushort_t* __restrict__ Bws,
    float4* __restrict__ outz, int nz4)
{
    const int tid = threadIdx.x;

    // fused zero of d_out for the atomic accumulate (grid covers it: 1536*256 >= nz4)
    {
        int zi = blockIdx.x * 256 + tid;
        if (zi < nz4) outz[zi] = make_float4(0.f, 0.f, 0.f, 0.f);
    }

    const int n  = tid & 127;
    const int rg = tid >> 7;                 // 0..1, each handles 8 rows
    const int r0 = blockIdx.x * 16;          // 16 rows per block, never crosses a support
    const int sup = r0 >> 13;
    const float* sd = (sup == 0) ? sd0 : ((sup == 1) ? sd1 : sd2);
    const int xrow0 = (r0 & (NN - 1)) + rg * 8;

    float acc[8];
#pragma unroll
    for (int i = 0; i < 8; ++i) acc[i] = 0.f;

    for (int c = 0; c < DD; c += 4) {
        float4 s4 = *reinterpret_cast<const float4*>(sd + c);
        float wv0 = s4.x * W[(c + 0) * DD + n];
        float wv1 = s4.y * W[(c + 1) * DD + n];
        float wv2 = s4.z * W[(c + 2) * DD + n];
        float wv3 = s4.w * W[(c + 3) * DD + n];
#pragma unroll
        for (int i = 0; i < 8; ++i) {
            float4 xv = *reinterpret_cast<const float4*>(&x[(size_t)(xrow0 + i) * DD + c]);
            acc[i] = fmaf(xv.x, wv0, acc[i]);
            acc[i] = fmaf(xv.y, wv1, acc[i]);
            acc[i] = fmaf(xv.z, wv2, acc[i]);
            acc[i] = fmaf(xv.w, wv3, acc[i]);
        }
    }

    const int t = n >> 4;
    const int nlo = n & 15;
#pragma unroll
    for (int i = 0; i < 8; ++i) {
        int r   = r0 + rg * 8 + i;
        int cc  = r >> 5;                    // global 32-wide k-chunk
        int rem = r & 31;
        int hi  = rem >> 3;                  // lane>>4 quadrant
        int j   = rem & 7;                   // element within fragment
        int ll  = hi * 16 + nlo;             // lane
        size_t idx = (((size_t)cc * 8 + t) * 64 + ll) * 8 + j;
        __bf16 b = (__bf16)acc[i];
        ushort_t u;
        __builtin_memcpy(&u, &b, sizeof(u));
        Bws[idx] = u;
    }
}

// ---------------------------------------------------------------------------
// Kernel 2: out += S_cat[8192 x 24576] @ B_cat[24576 x 128]  (split-K atomics)
// A staged through LDS via async global_load_lds, double-buffered (m97 pattern):
// the 16 KB tile for step c+1 is in flight during step c's cvt+MFMA phase,
// giving ~64 KB outstanding per CU (4 blocks) -> HBM stays saturated.
// LDS layout is XOR-swizzled (16B unit ^= row&7) via pre-swizzled GLOBAL source
// addresses (dest of global_load_lds must stay linear), so the stride-128B
// ds_read_b128 pattern is bank-conflict-free.
// ---------------------------------------------------------------------------
__global__ __launch_bounds__(256, 4) void spmm_kernel(
    const float* __restrict__ s0, const float* __restrict__ s1,
    const float* __restrict__ s2, const ushort_t* __restrict__ Bws,
    float* __restrict__ out)
{
    __shared__ float Alds[2][BM * 32];       // 2 x 16 KB

    const int tid  = threadIdx.x;
    const int lane = tid & 63;
    const int wave = tid >> 6;
    const int bid  = blockIdx.x;
    // XCD-aware mapping: low 3 bits (the round-robin XCD index) carry the split,
    // so each XCD sees only 2 splits -> its B slice (2 x 384 KB) is L2-resident.
    const int split = ((bid & 7) << 1) | ((bid >> 3) & 1);
    const int mblk  = bid >> 4;
    const int kbase = split * KSPLIT;
    const int m15   = lane & 15;
    const int q     = lane >> 4;
    const int mrow0 = mblk * BM;
    const int rloc  = wave * 32;             // wave's rows within the tile

    // staging geometry: 16B unit u = j*256 + tid; LDS unit u holds global
    // (row = u>>3, q16 = (u&7) ^ (row&7)) -> source pre-swizzle
    int srow[4], sq16[4];
#pragma unroll
    for (int jj = 0; jj < 4; ++jj) {
        int u = jj * 256 + tid;
        srow[jj] = u >> 3;
        sq16[jj] = (u & 7) ^ (srow[jj] & 7);
    }
    const int dunit0 = wave * 64;            // wave-uniform LDS dest base unit (+ jj*256)

    // swizzled read addresses (16B units): lane wants (row_l, k units q*2, q*2+1)
    int rdu[2][2];
#pragma unroll
    for (int ms = 0; ms < 2; ++ms) {
        int row_l = rloc + ms * 16 + m15;
        rdu[ms][0] = row_l * 8 + ((q * 2)     ^ (row_l & 7));
        rdu[ms][1] = row_l * 8 + ((q * 2 + 1) ^ (row_l & 7));
    }

    f32x4 acc[2][8];
#pragma unroll
    for (int ms = 0; ms < 2; ++ms)
#pragma unroll
        for (int t = 0; t < 8; ++t)
            acc[ms][t] = (f32x4){0.f, 0.f, 0.f, 0.f};

    const bf16x8* __restrict__ Bv = reinterpret_cast<const bf16x8*>(Bws);
    const int cg0 = kbase >> 5;

    auto stage = [&](int buf, int c) {
        const int kg = kbase + c * 32;
        const float* sp = (kg < NN) ? s0 : ((kg < 2 * NN) ? s1 : s2);
        const int kk = kg & (NN - 1);
#pragma unroll
        for (int jj = 0; jj < 4; ++jj) {
            const float* src = sp + (size_t)(mrow0 + srow[jj]) * NN + (kk + sq16[jj] * 4);
            float* dst = &Alds[buf][(size_t)(jj * 256 + dunit0) * 4];
            __builtin_amdgcn_global_load_lds((as1_u32*)src, (as3_u32*)dst, 16, 0, 0);
        }
    };

    stage(0, 0);
    int cur = 0;
    for (int c = 0; c < NSTEP; ++c) {
        // implicit s_waitcnt vmcnt(0) before s_barrier: buf[cur] (staged one full
        // compute phase ago) is ready; all waves' ds_reads of buf[cur^1] are done.
        __syncthreads();
        if (c + 1 < NSTEP) stage(cur ^ 1, c + 1);   // async, drains at next barrier

        bf16x8 af[2];
#pragma unroll
        for (int ms = 0; ms < 2; ++ms) {
            f32x4 f0 = *reinterpret_cast<const f32x4*>(&Alds[cur][rdu[ms][0] * 4]);
            f32x4 f1 = *reinterpret_cast<const f32x4*>(&Alds[cur][rdu[ms][1] * 4]);
            bf16x8 a;
            a[0] = (__bf16)f0[0]; a[1] = (__bf16)f0[1];
            a[2] = (__bf16)f0[2]; a[3] = (__bf16)f0[3];
            a[4] = (__bf16)f1[0]; a[5] = (__bf16)f1[1];
            a[6] = (__bf16)f1[2]; a[7] = (__bf16)f1[3];
            af[ms] = a;
        }

        const bf16x8* bp = Bv + (size_t)(cg0 + c) * 512 + lane;
#pragma unroll
        for (int t = 0; t < 8; ++t) {
            bf16x8 bf = bp[(size_t)t * 64];
            acc[0][t] = __builtin_amdgcn_mfma_f32_16x16x32_bf16(af[0], bf, acc[0][t], 0, 0, 0);
            acc[1][t] = __builtin_amdgcn_mfma_f32_16x16x32_bf16(af[1], bf, acc[1][t], 0, 0, 0);
        }
        cur ^= 1;
    }

    // C/D layout (m89-verified): col = lane&15, row = (lane>>4)*4 + reg
#pragma unroll
    for (int ms = 0; ms < 2; ++ms)
#pragma unroll
        for (int t = 0; t < 8; ++t)
#pragma unroll
            for (int r = 0; r < 4; ++r) {
                int row = mrow0 + rloc + ms * 16 + q * 4 + r;
                int col = t * 16 + m15;
                atomicAdd(out + (size_t)row * DD + col, acc[ms][t][r]);
            }
}

// ---------------------------------------------------------------------------
// Kernel 3: in-place relu on d_out
// ---------------------------------------------------------------------------
__global__ __launch_bounds__(256) void relu_kernel(float4* __restrict__ out)
{
    int i = blockIdx.x * 256 + threadIdx.x;
    float4 v = out[i];
    v.x = fmaxf(v.x, 0.f);
    v.y = fmaxf(v.y, 0.f);
    v.z = fmaxf(v.z, 0.f);
    v.w = fmaxf(v.w, 0.f);
    out[i] = v;
}

extern "C" void kernel_launch(void* const* d_in, const int* in_sizes, int n_in,
                              void* d_out, int out_size, void* d_ws, size_t ws_size,
                              hipStream_t stream)
{
    (void)in_sizes; (void)n_in; (void)ws_size;
    const float* x   = (const float*)d_in[0];
    const float* s0  = (const float*)d_in[1];
    const float* s1  = (const float*)d_in[2];
    const float* s2  = (const float*)d_in[3];
    const float* W   = (const float*)d_in[4];
    const float* sd0 = (const float*)d_in[5];
    const float* sd1 = (const float*)d_in[6];
    const float* sd2 = (const float*)d_in[7];
    float* out = (float*)d_out;
    ushort_t* Bws = (ushort_t*)d_ws;   // needs 24576*128*2 = 6.3 MB

    // d_out zeroing is fused into bprep_kernel (one fewer dispatch)
    bprep_kernel<<<KTOT / 16, 256, 0, stream>>>(x, W, sd0, sd1, sd2, Bws,
                                                (float4*)d_out, out_size / 4);
    spmm_kernel<<<(NN / BM) * SPLITS, 256, 0, stream>>>(s0, s1, s2, Bws, out);
    relu_kernel<<<out_size / 1024, 256, 0, stream>>>((float4*)d_out);
}